// Round 10
// baseline (17607.730 us; speedup 1.0000x reference)
//
#include <hip/hip_runtime.h>
#include <cstdint>

// ---------------- problem constants ----------------
constexpr int B_ = 4, N_ = 16384, M_ = 2048;
constexpr int COLS0 = B_ * M_ * 32;   // 262144
constexpr int COLS1 = B_ * M_ * 64;   // 524288

// ---------------- workspace layout (bytes), total < 6 MiB ----------------
constexpr size_t OFF_NEWXYZ = 0;                                   // B*3*M fp32
constexpr size_t OFF_NIDX0  = (size_t)B_ * 3 * M_ * 4;             // 98304
constexpr size_t OFF_NIDX1  = OFF_NIDX0 + (size_t)COLS0 * 4;
constexpr size_t OFF_STATS  = OFF_NIDX1 + (size_t)COLS1 * 4;
constexpr size_t STATS_VALS = 64 * 2 * 128;                        // doubles per layer region
constexpr size_t OFF_COEF   = OFF_STATS + 6 * STATS_VALS * 8;      // 6 x 128 float4

// ---------------- FPS in float64 (proven exact by output-0 pass; verbatim) ----------------
__global__ __launch_bounds__(1024) void fps_kernel(const float* __restrict__ xyz,
                                                   float* __restrict__ newxyz,
                                                   float* __restrict__ outxyz) {
#pragma clang fp contract(off)
  int b = blockIdx.x, t = threadIdx.x;
  const float* xb = xyz + (size_t)b * 3 * N_;
  float px[16], py[16], pz[16];
  double dd[16];
#pragma unroll
  for (int i = 0; i < 16; ++i) {
    int n = t + (i << 10);
    px[i] = xb[n]; py[i] = xb[N_ + n]; pz[i] = xb[2 * N_ + n];
    dd[i] = 1e10;
  }
  __shared__ float  s_out[3 * M_];
  __shared__ double s_val[16];
  __shared__ int    s_idx[16];
  __shared__ int    s_w;
  float fx = xb[0], fy = xb[N_], fz = xb[2 * N_];
  if (t == 0) { s_out[0] = fx; s_out[M_] = fy; s_out[2 * M_] = fz; }
  int lane = t & 63, wid = t >> 6;
  for (int s = 1; s < M_; ++s) {
    double fdx = (double)fx, fdy = (double)fy, fdz = (double)fz;
    double bv = -1.0; int bi = 0x7fffffff;
#pragma unroll
    for (int i = 0; i < 16; ++i) {
      double dx = (double)px[i] - fdx;
      double dy = (double)py[i] - fdy;
      double dz = (double)pz[i] - fdz;
      double d = (dx * dx + dy * dy) + dz * dz;
      double dm = dd[i];
      if (d < dm) dm = d;
      dd[i] = dm;
      if (dm > bv) { bv = dm; bi = t + (i << 10); }
    }
#pragma unroll
    for (int off = 1; off < 64; off <<= 1) {
      double ov = __shfl_xor(bv, off);
      int    oi = __shfl_xor(bi, off);
      if (ov > bv || (ov == bv && oi < bi)) { bv = ov; bi = oi; }
    }
    if (lane == 0) { s_val[wid] = bv; s_idx[wid] = bi; }
    __syncthreads();
    if (wid == 0) {
      double v = (lane < 16) ? s_val[lane] : -1.0;
      int   ii = (lane < 16) ? s_idx[lane] : 0x7fffffff;
#pragma unroll
      for (int off = 1; off < 16; off <<= 1) {
        double ov = __shfl_xor(v, off);
        int    oi = __shfl_xor(ii, off);
        if (ov > v || (ov == v && oi < ii)) { v = ov; ii = oi; }
      }
      if (lane == 0) s_w = ii;
    }
    __syncthreads();
    int w = s_w;
    fx = xb[w]; fy = xb[N_ + w]; fz = xb[2 * N_ + w];
    if (t == 0) { s_out[s] = fx; s_out[M_ + s] = fy; s_out[2 * M_ + s] = fz; }
  }
  __syncthreads();
  for (int e = t; e < 3 * M_; e += 1024) {
    float v = s_out[e];
    newxyz[(size_t)b * 3 * M_ + e] = v;
    outxyz[(size_t)b * 3 * M_ + e] = v;
  }
}

// ---------------- ball query: fp32 with FMA-contracted dot (BLAS/XLA rounding) ----------------
// ref np/XLA: sq terms = materialized squares + sequential reduce (NO fma);
//             dot = gemm k-loop: acc = fma(c_d, x_d, acc), d ascending;
//             d2 = (sqc + sqx) - 2*dot;  membership: d2 < fl32(r^2), strict.
template <int KNB>
__global__ __launch_bounds__(256) void bq_kernel(const float* __restrict__ xyz,
                                                 const float* __restrict__ newxyz,
                                                 int* __restrict__ nidx, float r2) {
#pragma clang fp contract(off)
  int q = blockIdx.x * 256 + threadIdx.x;    // q < B*M
  int b = q >> 11;
  int m = q & 2047;
  const float* xb = xyz + (size_t)b * 3 * N_;
  float cx = newxyz[((size_t)b * 3 + 0) * M_ + m];
  float cy = newxyz[((size_t)b * 3 + 1) * M_ + m];
  float cz = newxyz[((size_t)b * 3 + 2) * M_ + m];
  float sqc = (cx * cx + cy * cy) + cz * cz;       // no fma (contract off)
  int cnt = 0, first = 0;
  for (int n = 0; n < N_; ++n) {
    float x = xb[n], y = xb[N_ + n], z = xb[2 * N_ + n];
    float sqx = (x * x + y * y) + z * z;           // no fma
    float dot = fmaf(cz, z, fmaf(cy, y, cx * x));  // fma chain, d ascending
    float d2 = (sqc + sqx) - 2.0f * dot;           // 2*dot exact; one rounding
    if (d2 < r2) {
      if (cnt == 0) first = n;
      nidx[(size_t)q * KNB + cnt] = n;
      if (++cnt == KNB) break;                     // first K ascending == K smallest indices
    }
  }
  for (int s = cnt; s < KNB; ++s) nidx[(size_t)q * KNB + s] = first;  // cnt==0 -> 0
}

// ---------------- per-channel stats accumulate in FLOAT64 (butterfly + bucketed atomics) ------
__device__ __forceinline__ void stat_accum(float acc, int o, int cout, double* stats, int part) {
  double v1 = (double)acc, v2 = (double)acc * (double)acc;
#pragma unroll
  for (int off = 1; off < 64; off <<= 1) {
    v1 += __shfl_xor(v1, off);
    v2 += __shfl_xor(v2, off);
  }
  if (threadIdx.x == 0) {
    atomicAdd(stats + ((size_t)part * 2 + 0) * cout + o, v1);
    atomicAdd(stats + ((size_t)part * 2 + 1) * cout + o, v2);
  }
}

// ---------------- fp32 recompute-chain kernel, fp64 BN stats, ref-order BN apply --------------
// STAGE 0/1/2: stats of layer-0/1/2 conv.  STAGE 3: apply all + max over K + write output.
// coef float4 = (mu, rstd, g, b); apply: z = relu(((acc - mu)*rstd)*g + b)   [ref op order]
template <int C1, int C2, int KNB, int STAGE>
__global__ __launch_bounds__(64) void chain_kernel(
    const float* __restrict__ w0, const float* __restrict__ w1, const float* __restrict__ w2,
    const float* __restrict__ xyz, const float* __restrict__ feat,
    const int* __restrict__ nidx, const float* __restrict__ newxyz,
    const float4* __restrict__ coef0, const float4* __restrict__ coef1,
    const float4* __restrict__ coef2,
    double* __restrict__ stats, float* __restrict__ outFeats, int chBase)
{
  constexpr int Z0R = (STAGE >= 1) ? 64 : 1;
  constexpr int Z1R = (STAGE >= 2) ? 64 : 1;
  __shared__ float z0[Z0R][C1 + 1];
  __shared__ float z1[Z1R][C2 + 1];
  int lane = threadIdx.x;
  int col = blockIdx.x * 64 + lane;
  int part = blockIdx.x & 63;

  // ---- gather x[67] = [member - center ; features(member)] ----
  float x[67];
  {
    int b = col / (M_ * KNB);
    int rem = col - b * (M_ * KNB);
    int m = rem / KNB;
    int n = nidx[col];
    const float* xb = xyz + (size_t)b * 3 * N_;
    x[0] = xb[n]          - newxyz[((size_t)b * 3 + 0) * M_ + m];
    x[1] = xb[N_ + n]     - newxyz[((size_t)b * 3 + 1) * M_ + m];
    x[2] = xb[2 * N_ + n] - newxyz[((size_t)b * 3 + 2) * M_ + m];
    const float* fb = feat + (size_t)b * 64 * N_;
#pragma unroll
    for (int c = 0; c < 64; ++c) x[3 + c] = fb[(size_t)c * N_ + n];
  }

  if constexpr (STAGE == 0) {
    for (int o = 0; o < C1; ++o) {
      const float* wr = w0 + (size_t)o * 67;
      float acc = 0.f;
#pragma unroll
      for (int c = 0; c < 67; ++c) acc += wr[c] * x[c];
      stat_accum(acc, o, C1, stats, part);
    }
    return;
  }

  // ---- layer 0: z0 = relu(bn0(w0·x)) ----
  for (int o = 0; o < C1; ++o) {
    const float* wr = w0 + (size_t)o * 67;
    float acc = 0.f;
#pragma unroll
    for (int c = 0; c < 67; ++c) acc += wr[c] * x[c];
    float4 cf = coef0[o];
    z0[lane][o] = fmaxf(((acc - cf.x) * cf.y) * cf.z + cf.w, 0.f);
  }

  if constexpr (STAGE == 1) {
    for (int o = 0; o < C2; ++o) {
      const float* wr = w1 + (size_t)o * C1;
      float acc = 0.f;
#pragma unroll
      for (int c = 0; c < C1; ++c) acc += wr[c] * z0[lane][c];
      stat_accum(acc, o, C2, stats, part);
    }
    return;
  }

  // ---- layer 1: z1 = relu(bn1(w1·z0)) ----
  for (int o = 0; o < C2; ++o) {
    const float* wr = w1 + (size_t)o * C1;
    float acc = 0.f;
#pragma unroll
    for (int c = 0; c < C1; ++c) acc += wr[c] * z0[lane][c];
    float4 cf = coef1[o];
    z1[lane][o] = fmaxf(((acc - cf.x) * cf.y) * cf.z + cf.w, 0.f);
  }

  if constexpr (STAGE == 2) {
    for (int o = 0; o < 128; ++o) {
      const float* wr = w2 + (size_t)o * C2;
      float acc = 0.f;
#pragma unroll
      for (int c = 0; c < C2; ++c) acc += wr[c] * z1[lane][c];
      stat_accum(acc, o, 128, stats, part);
    }
    return;
  }

  // ---- STAGE 3: layer 2 + BN + ReLU + max over K + write fp32 output ----
  for (int o = 0; o < 128; ++o) {
    const float* wr = w2 + (size_t)o * C2;
    float acc = 0.f;
#pragma unroll
    for (int c = 0; c < C2; ++c) acc += wr[c] * z1[lane][c];
    float4 cf = coef2[o];
    float z = fmaxf(((acc - cf.x) * cf.y) * cf.z + cf.w, 0.f);
    if constexpr (KNB == 64) {
#pragma unroll
      for (int off = 1; off < 64; off <<= 1) z = fmaxf(z, __shfl_xor(z, off));
      if (lane == 0) {
        int grp = blockIdx.x;                 // = b*M + m
        int b = grp >> 11, m = grp & 2047;
        outFeats[((size_t)b * 256 + chBase + o) * M_ + m] = z;
      }
    } else {                                   // KNB == 32: two groups per wave
#pragma unroll
      for (int off = 1; off < 32; off <<= 1) z = fmaxf(z, __shfl_xor(z, off));
      if ((lane & 31) == 0) {
        int grp = blockIdx.x * 2 + (lane >> 5);
        int b = grp >> 11, m = grp & 2047;
        outFeats[((size_t)b * 256 + chBase + o) * M_ + m] = z;
      }
    }
  }
}

// ---------------- fold fp64 BN stats into per-channel (mu, rstd, g, b) ----------------
__global__ void coef_kernel(const double* __restrict__ stats, const float* __restrict__ g,
                            const float* __restrict__ bb, float4* __restrict__ coef,
                            int cout, double invcnt) {
  int ch = threadIdx.x;
  if (ch >= cout) return;
  double s1 = 0.0, s2 = 0.0;
  for (int p = 0; p < 64; ++p) {
    s1 += stats[((size_t)p * 2 + 0) * cout + ch];
    s2 += stats[((size_t)p * 2 + 1) * cout + ch];
  }
  double mean = s1 * invcnt;
  double var = s2 * invcnt - mean * mean;
  double rstd = 1.0 / sqrt(var + 1e-5);
  coef[ch] = make_float4((float)mean, (float)rstd, g[ch], bb[ch]);
}

// ---------------- launcher ----------------
extern "C" void kernel_launch(void* const* d_in, const int* in_sizes, int n_in,
                              void* d_out, int out_size, void* d_ws, size_t ws_size,
                              hipStream_t stream) {
  const float* xyz  = (const float*)d_in[0];
  const float* feat = (const float*)d_in[1];
  const float* w00 = (const float*)d_in[2],  *g00 = (const float*)d_in[3],  *b00 = (const float*)d_in[4];
  const float* w01 = (const float*)d_in[5],  *g01 = (const float*)d_in[6],  *b01 = (const float*)d_in[7];
  const float* w02 = (const float*)d_in[8],  *g02 = (const float*)d_in[9],  *b02 = (const float*)d_in[10];
  const float* w10 = (const float*)d_in[11], *g10 = (const float*)d_in[12], *b10 = (const float*)d_in[13];
  const float* w11 = (const float*)d_in[14], *g11 = (const float*)d_in[15], *b11 = (const float*)d_in[16];
  const float* w12 = (const float*)d_in[17], *g12 = (const float*)d_in[18], *b12 = (const float*)d_in[19];

  char* ws = (char*)d_ws;
  float*  newxyz = (float*)(ws + OFF_NEWXYZ);
  int*    nidx0  = (int*)(ws + OFF_NIDX0);
  int*    nidx1  = (int*)(ws + OFF_NIDX1);
  double* stats  = (double*)(ws + OFF_STATS);
  float4* coef   = (float4*)(ws + OFF_COEF);
  float* outF = (float*)d_out;
  float* outFeats = outF + (size_t)B_ * 3 * M_;

  hipMemsetAsync(ws + OFF_STATS, 0, 6 * STATS_VALS * 8, stream);
  fps_kernel<<<B_, 1024, 0, stream>>>(xyz, newxyz, outF);
  bq_kernel<32><<<(B_ * M_) / 256, 256, 0, stream>>>(xyz, newxyz, nidx0, (float)(0.2 * 0.2));
  bq_kernel<64><<<(B_ * M_) / 256, 256, 0, stream>>>(xyz, newxyz, nidx1, (float)(0.4 * 0.4));

  float4* c00 = coef + 0 * 128; float4* c01 = coef + 1 * 128; float4* c02 = coef + 2 * 128;
  float4* c10 = coef + 3 * 128; float4* c11 = coef + 4 * 128; float4* c12 = coef + 5 * 128;
  double* st0 = stats + 0 * STATS_VALS; double* st1 = stats + 1 * STATS_VALS;
  double* st2 = stats + 2 * STATS_VALS; double* st3 = stats + 3 * STATS_VALS;
  double* st4 = stats + 4 * STATS_VALS; double* st5 = stats + 5 * STATS_VALS;
  int gr0 = COLS0 / 64, gr1 = COLS1 / 64;

  // ---- scale 0 (K=32): 67->64->64->128, recompute-chain, fp64 stats ----
  chain_kernel<64, 64, 32, 0><<<gr0, 64, 0, stream>>>(
      w00, w01, w02, xyz, feat, nidx0, newxyz, nullptr, nullptr, nullptr, st0, nullptr, 0);
  coef_kernel<<<1, 128, 0, stream>>>(st0, g00, b00, c00, 64, 1.0 / COLS0);
  chain_kernel<64, 64, 32, 1><<<gr0, 64, 0, stream>>>(
      w00, w01, w02, xyz, feat, nidx0, newxyz, c00, nullptr, nullptr, st1, nullptr, 0);
  coef_kernel<<<1, 128, 0, stream>>>(st1, g01, b01, c01, 64, 1.0 / COLS0);
  chain_kernel<64, 64, 32, 2><<<gr0, 64, 0, stream>>>(
      w00, w01, w02, xyz, feat, nidx0, newxyz, c00, c01, nullptr, st2, nullptr, 0);
  coef_kernel<<<1, 128, 0, stream>>>(st2, g02, b02, c02, 128, 1.0 / COLS0);
  chain_kernel<64, 64, 32, 3><<<gr0, 64, 0, stream>>>(
      w00, w01, w02, xyz, feat, nidx0, newxyz, c00, c01, c02, nullptr, outFeats, 0);

  // ---- scale 1 (K=64): 67->64->96->128 ----
  chain_kernel<64, 96, 64, 0><<<gr1, 64, 0, stream>>>(
      w10, w11, w12, xyz, feat, nidx1, newxyz, nullptr, nullptr, nullptr, st3, nullptr, 0);
  coef_kernel<<<1, 128, 0, stream>>>(st3, g10, b10, c10, 64, 1.0 / COLS1);
  chain_kernel<64, 96, 64, 1><<<gr1, 64, 0, stream>>>(
      w10, w11, w12, xyz, feat, nidx1, newxyz, c10, nullptr, nullptr, st4, nullptr, 0);
  coef_kernel<<<1, 128, 0, stream>>>(st4, g11, b11, c11, 96, 1.0 / COLS1);
  chain_kernel<64, 96, 64, 2><<<gr1, 64, 0, stream>>>(
      w10, w11, w12, xyz, feat, nidx1, newxyz, c10, c11, nullptr, st5, nullptr, 0);
  coef_kernel<<<1, 128, 0, stream>>>(st5, g12, b12, c12, 128, 1.0 / COLS1);
  chain_kernel<64, 96, 64, 3><<<gr1, 64, 0, stream>>>(
      w10, w11, w12, xyz, feat, nidx1, newxyz, c10, c11, c12, nullptr, outFeats, 128);
}

// Round 12
// 5128.466 us; speedup vs baseline: 3.4333x; 3.4333x over previous
//
#include <hip/hip_runtime.h>
#include <cstdint>

// ---------------- problem constants ----------------
constexpr int B_ = 4, N_ = 16384, M_ = 2048;
constexpr int COLS0 = B_ * M_ * 32;   // 262144
constexpr int COLS1 = B_ * M_ * 64;   // 524288

// ---------------- workspace layout (bytes), total ~196 MiB (well under 240 MB proven-safe) ----
constexpr size_t OFF_NEWXYZ = 0;                                   // B*3*M fp32
constexpr size_t OFF_NIDX0  = (size_t)B_ * 3 * M_ * 4;             // 98304
constexpr size_t OFF_NIDX1  = OFF_NIDX0 + (size_t)COLS0 * 4;
constexpr size_t OFF_STATS  = OFF_NIDX1 + (size_t)COLS1 * 4;
constexpr size_t STATS_VALS = 64 * 2 * 128;                        // doubles per layer region
constexpr size_t OFF_COEF   = OFF_STATS + 6 * STATS_VALS * 8;      // 6 x 128 float4
constexpr size_t OFF_Z      = OFF_COEF + 6 * 128 * 16;
// Z: per-64-column records [rec][96 ch][64 lanes] fp32; COLS1/64 recs -> 201.3 MB
constexpr int ZSTRIDE = 96 * 64;                                   // floats per record

// ---------------- FPS: fp32 (proven ≡ fp64 on this data), packed-u64 argmax reduce ------------
__global__ __launch_bounds__(512) void fps_kernel(const float* __restrict__ xyz,
                                                  float* __restrict__ newxyz,
                                                  float* __restrict__ outxyz) {
#pragma clang fp contract(off)
  int b = blockIdx.x, t = threadIdx.x;
  const float* xb = xyz + (size_t)b * 3 * N_;
  float px[32], py[32], pz[32], dd[32];
#pragma unroll
  for (int i = 0; i < 32; ++i) {
    int n = t + (i << 9);
    px[i] = xb[n]; py[i] = xb[N_ + n]; pz[i] = xb[2 * N_ + n];
    dd[i] = 1e10f;
  }
  __shared__ float s_out[3 * M_];
  __shared__ unsigned long long s_red[8];
  __shared__ int s_w;
  float fx = xb[0], fy = xb[N_], fz = xb[2 * N_];
  if (t == 0) { s_out[0] = fx; s_out[M_] = fy; s_out[2 * M_] = fz; }
  int lane = t & 63, wid = t >> 6;
  for (int s = 1; s < M_; ++s) {
    float bv = -1.f; int bi = 0;
#pragma unroll
    for (int i = 0; i < 32; ++i) {
      float dx = px[i] - fx, dy = py[i] - fy, dz = pz[i] - fz;
      float d = (dx * dx + dy * dy) + dz * dz;   // verbatim R3 arithmetic (no FMA)
      float dm = dd[i];
      if (d < dm) dm = d;
      dd[i] = dm;
      if (dm > bv) { bv = dm; bi = t + (i << 9); }  // in-thread tie -> smaller n kept
    }
    // key: dist bits (>=0, monotone) high, ~idx low => max key = max dist, tie -> min idx
    unsigned long long key =
        ((unsigned long long)__float_as_uint(bv) << 32) | (unsigned)(0xFFFFFFFFu - (unsigned)bi);
#pragma unroll
    for (int off = 1; off < 64; off <<= 1) {
      unsigned long long o = __shfl_xor(key, off);
      if (o > key) key = o;
    }
    if (lane == 0) s_red[wid] = key;
    __syncthreads();
    if (wid == 0) {
      unsigned long long k2 = (lane < 8) ? s_red[lane] : 0ull;
#pragma unroll
      for (int off = 1; off < 8; off <<= 1) {
        unsigned long long o = __shfl_xor(k2, off);
        if (o > k2) k2 = o;
      }
      if (lane == 0) s_w = (int)(0xFFFFFFFFu - (unsigned)(k2 & 0xFFFFFFFFull));
    }
    __syncthreads();
    int w = s_w;
    fx = xb[w]; fy = xb[N_ + w]; fz = xb[2 * N_ + w];
    if (t == 0) { s_out[s] = fx; s_out[M_ + s] = fy; s_out[2 * M_ + s] = fz; }
  }
  __syncthreads();
  for (int e = t; e < 3 * M_; e += 512) {
    float v = s_out[e];
    newxyz[(size_t)b * 3 * M_ + e] = v;
    outxyz[(size_t)b * 3 * M_ + e] = v;
  }
}

// ---------------- ball query: wave per center, ballot-prefix, FMA dot (the proven rounding) ---
template <int KNB>
__global__ __launch_bounds__(256) void bq_kernel(const float* __restrict__ xyz,
                                                 const float* __restrict__ newxyz,
                                                 int* __restrict__ nidx, float r2) {
#pragma clang fp contract(off)
  int t = threadIdx.x, lane = t & 63, wq = t >> 6;
  int q = blockIdx.x * 4 + wq;               // q < B*M
  int b = q >> 11, m = q & 2047;
  const float* xb = xyz + (size_t)b * 3 * N_;
  float cx = newxyz[((size_t)b * 3 + 0) * M_ + m];
  float cy = newxyz[((size_t)b * 3 + 1) * M_ + m];
  float cz = newxyz[((size_t)b * 3 + 2) * M_ + m];
  float sqc = (cx * cx + cy * cy) + cz * cz;         // no fma
  int found = 0, first = 0;
  for (int c = 0; c < N_ / 64; ++c) {
    int n = c * 64 + lane;
    float x = xb[n], y = xb[N_ + n], z = xb[2 * N_ + n];
    float sqx = (x * x + y * y) + z * z;             // no fma
    float dot = fmaf(cz, z, fmaf(cy, y, cx * x));    // fma chain (proven ref rounding, R10)
    float d2 = (sqc + sqx) - 2.0f * dot;
    bool in = d2 < r2;
    unsigned long long mask = __ballot(in);
    if (mask) {
      if (found == 0) first = c * 64 + (__ffsll((long long)mask) - 1);
      int pos = found + __popcll(mask & ((1ull << lane) - 1ull));
      if (in && pos < KNB) nidx[(size_t)q * KNB + pos] = n;
      found += __popcll(mask);
      if (found >= KNB) break;                       // first K ascending == K smallest indices
    }
  }
  if (found < KNB) {
    int fill = (found == 0) ? 0 : first;
    for (int s = found + lane; s < KNB; s += 64) nidx[(size_t)q * KNB + s] = fill;
  }
}

// ---------------- per-channel stats: fp32 butterfly partials -> f64 bucketed atomics ----------
__device__ __forceinline__ void stat_accum(float acc, int o, int cout, double* stats,
                                           int part, int lane) {
  float v1 = acc, v2 = acc * acc;
#pragma unroll
  for (int off = 1; off < 64; off <<= 1) {
    v1 += __shfl_xor(v1, off);
    v2 += __shfl_xor(v2, off);
  }
  if (lane == 0) {
    atomicAdd(stats + ((size_t)part * 2 + 0) * cout + o, (double)v1);
    atomicAdd(stats + ((size_t)part * 2 + 1) * cout + o, (double)v2);
  }
}

// ---------------- layer 0: gather -> conv(67->64) -> record store + stats ---------------------
template <int KNB>
__global__ __launch_bounds__(256) void convL0_kernel(
    const float* __restrict__ w0,              // [64][67] raw
    const float* __restrict__ xyz, const float* __restrict__ feat,
    const int* __restrict__ nidx, const float* __restrict__ newxyz,
    float* __restrict__ Z, double* __restrict__ stats) {
  int lane = threadIdx.x & 63, wq = threadIdx.x >> 6;
  int rec = blockIdx.x * 4 + wq;
  int col = rec * 64 + lane;
  float x[67];
  {
    int b = col / (M_ * KNB);
    int rem = col - b * (M_ * KNB);
    int m = rem / KNB;
    int n = nidx[col];
    const float* xb = xyz + (size_t)b * 3 * N_;
    x[0] = xb[n]          - newxyz[((size_t)b * 3 + 0) * M_ + m];
    x[1] = xb[N_ + n]     - newxyz[((size_t)b * 3 + 1) * M_ + m];
    x[2] = xb[2 * N_ + n] - newxyz[((size_t)b * 3 + 2) * M_ + m];
    const float* fb = feat + (size_t)b * 64 * N_;
#pragma unroll
    for (int c = 0; c < 64; ++c) x[3 + c] = fb[(size_t)c * N_ + n];   // L2/L3-resident
  }
  float* zr = Z + (size_t)rec * ZSTRIDE;
  int part = rec & 63;
  for (int o = 0; o < 64; ++o) {
    const float* wr = w0 + (size_t)o * 67;     // wave-uniform -> scalar loads
    float acc = 0.f;
#pragma unroll
    for (int c = 0; c < 67; ++c) acc += wr[c] * x[c];
    zr[o * 64 + lane] = acc;                   // coalesced 256B row store
    stat_accum(acc, o, 64, stats, part, lane);
  }
}

// ---------------- mid layer: record load + BN-apply -> conv -> in-place store + stats ---------
template <int CIN, int COUT>
__global__ __launch_bounds__(256) void convMid_kernel(
    const float* __restrict__ w,               // [COUT][CIN] raw
    const float4* __restrict__ coefIn,         // prev layer (mu, rstd, g, b)
    float* __restrict__ Z, double* __restrict__ stats) {
  int lane = threadIdx.x & 63, wq = threadIdx.x >> 6;
  int rec = blockIdx.x * 4 + wq;
  float* zr = Z + (size_t)rec * ZSTRIDE;
  float x[CIN];
#pragma unroll
  for (int c = 0; c < CIN; ++c) {              // load all to regs, then safe in-place overwrite
    float v = zr[c * 64 + lane];
    float4 cf = coefIn[c];
    x[c] = fmaxf(((v - cf.x) * cf.y) * cf.z + cf.w, 0.f);   // ref op order
  }
  int part = rec & 63;
  for (int o = 0; o < COUT; ++o) {
    const float* wr = w + (size_t)o * CIN;
    float acc = 0.f;
#pragma unroll
    for (int c = 0; c < CIN; ++c) acc += wr[c] * x[c];
    zr[o * 64 + lane] = acc;
    stat_accum(acc, o, COUT, stats, part, lane);
  }
}

// ---------------- last layer, pass A: stats only (conv result discarded) ----------------------
template <int CIN>
__global__ __launch_bounds__(256) void convLastStats_kernel(
    const float* __restrict__ w, const float4* __restrict__ coefIn,
    const float* __restrict__ Z, double* __restrict__ stats) {
  int lane = threadIdx.x & 63, wq = threadIdx.x >> 6;
  int rec = blockIdx.x * 4 + wq;
  const float* zr = Z + (size_t)rec * ZSTRIDE;
  float x[CIN];
#pragma unroll
  for (int c = 0; c < CIN; ++c) {
    float v = zr[c * 64 + lane];
    float4 cf = coefIn[c];
    x[c] = fmaxf(((v - cf.x) * cf.y) * cf.z + cf.w, 0.f);
  }
  int part = rec & 63;
  for (int o = 0; o < 128; ++o) {
    const float* wr = w + (size_t)o * CIN;
    float acc = 0.f;
#pragma unroll
    for (int c = 0; c < CIN; ++c) acc += wr[c] * x[c];
    stat_accum(acc, o, 128, stats, part, lane);
  }
}

// ---------------- last layer, pass B: recompute conv + BN + ReLU + max over K + write out -----
template <int CIN, int KNB>
__global__ __launch_bounds__(256) void convLastPool_kernel(
    const float* __restrict__ w, const float4* __restrict__ coefIn,
    const float4* __restrict__ coefOut,
    const float* __restrict__ Z, float* __restrict__ outFeats, int chBase) {
  int lane = threadIdx.x & 63, wq = threadIdx.x >> 6;
  int rec = blockIdx.x * 4 + wq;
  const float* zr = Z + (size_t)rec * ZSTRIDE;
  float x[CIN];
#pragma unroll
  for (int c = 0; c < CIN; ++c) {
    float v = zr[c * 64 + lane];
    float4 cf = coefIn[c];
    x[c] = fmaxf(((v - cf.x) * cf.y) * cf.z + cf.w, 0.f);
  }
  for (int o = 0; o < 128; ++o) {
    const float* wr = w + (size_t)o * CIN;
    float acc = 0.f;
#pragma unroll
    for (int c = 0; c < CIN; ++c) acc += wr[c] * x[c];
    float4 cf = coefOut[o];
    float z = fmaxf(((acc - cf.x) * cf.y) * cf.z + cf.w, 0.f);
    if (KNB == 64) {
#pragma unroll
      for (int off = 1; off < 64; off <<= 1) z = fmaxf(z, __shfl_xor(z, off));
      if (lane == 0) {
        int b = rec >> 11, m = rec & 2047;
        outFeats[((size_t)b * 256 + chBase + o) * M_ + m] = z;
      }
    } else {                                    // KNB == 32: two groups per wave
#pragma unroll
      for (int off = 1; off < 32; off <<= 1) z = fmaxf(z, __shfl_xor(z, off));
      if ((lane & 31) == 0) {
        int grp = rec * 2 + (lane >> 5);
        int b = grp >> 11, m = grp & 2047;
        outFeats[((size_t)b * 256 + chBase + o) * M_ + m] = z;
      }
    }
  }
}

// ---------------- fold fp64 BN stats into per-channel (mu, rstd, g, b) ----------------
__global__ void coef_kernel(const double* __restrict__ stats, const float* __restrict__ g,
                            const float* __restrict__ bb, float4* __restrict__ coef,
                            int cout, double invcnt) {
  int ch = threadIdx.x;
  if (ch >= cout) return;
  double s1 = 0.0, s2 = 0.0;
  for (int p = 0; p < 64; ++p) {
    s1 += stats[((size_t)p * 2 + 0) * cout + ch];
    s2 += stats[((size_t)p * 2 + 1) * cout + ch];
  }
  double mean = s1 * invcnt;
  double var = s2 * invcnt - mean * mean;
  double rstd = 1.0 / sqrt(var + 1e-5);
  coef[ch] = make_float4((float)mean, (float)rstd, g[ch], bb[ch]);
}

// ---------------- launcher ----------------
extern "C" void kernel_launch(void* const* d_in, const int* in_sizes, int n_in,
                              void* d_out, int out_size, void* d_ws, size_t ws_size,
                              hipStream_t stream) {
  const float* xyz  = (const float*)d_in[0];
  const float* feat = (const float*)d_in[1];
  const float* w00 = (const float*)d_in[2],  *g00 = (const float*)d_in[3],  *b00 = (const float*)d_in[4];
  const float* w01 = (const float*)d_in[5],  *g01 = (const float*)d_in[6],  *b01 = (const float*)d_in[7];
  const float* w02 = (const float*)d_in[8],  *g02 = (const float*)d_in[9],  *b02 = (const float*)d_in[10];
  const float* w10 = (const float*)d_in[11], *g10 = (const float*)d_in[12], *b10 = (const float*)d_in[13];
  const float* w11 = (const float*)d_in[14], *g11 = (const float*)d_in[15], *b11 = (const float*)d_in[16];
  const float* w12 = (const float*)d_in[17], *g12 = (const float*)d_in[18], *b12 = (const float*)d_in[19];

  char* ws = (char*)d_ws;
  float*  newxyz = (float*)(ws + OFF_NEWXYZ);
  int*    nidx0  = (int*)(ws + OFF_NIDX0);
  int*    nidx1  = (int*)(ws + OFF_NIDX1);
  double* stats  = (double*)(ws + OFF_STATS);
  float4* coef   = (float4*)(ws + OFF_COEF);
  float*  Z      = (float*)(ws + OFF_Z);
  float* outF = (float*)d_out;
  float* outFeats = outF + (size_t)B_ * 3 * M_;

  hipMemsetAsync(ws + OFF_STATS, 0, 6 * STATS_VALS * 8, stream);
  fps_kernel<<<B_, 512, 0, stream>>>(xyz, newxyz, outF);
  bq_kernel<32><<<(B_ * M_) / 4, 256, 0, stream>>>(xyz, newxyz, nidx0, (float)(0.2 * 0.2));
  bq_kernel<64><<<(B_ * M_) / 4, 256, 0, stream>>>(xyz, newxyz, nidx1, (float)(0.4 * 0.4));

  float4* c00 = coef + 0 * 128; float4* c01 = coef + 1 * 128; float4* c02 = coef + 2 * 128;
  float4* c10 = coef + 3 * 128; float4* c11 = coef + 4 * 128; float4* c12 = coef + 5 * 128;
  double* st0 = stats + 0 * STATS_VALS; double* st1 = stats + 1 * STATS_VALS;
  double* st2 = stats + 2 * STATS_VALS; double* st3 = stats + 3 * STATS_VALS;
  double* st4 = stats + 4 * STATS_VALS; double* st5 = stats + 5 * STATS_VALS;
  int gb0 = (COLS0 / 64) / 4, gb1 = (COLS1 / 64) / 4;   // 4 records per 256-thr block

  // ---- scale 0 (K=32): 67->64->64->128 ----
  convL0_kernel<32><<<gb0, 256, 0, stream>>>(w00, xyz, feat, nidx0, newxyz, Z, st0);
  coef_kernel<<<1, 128, 0, stream>>>(st0, g00, b00, c00, 64, 1.0 / COLS0);
  convMid_kernel<64, 64><<<gb0, 256, 0, stream>>>(w01, c00, Z, st1);
  coef_kernel<<<1, 128, 0, stream>>>(st1, g01, b01, c01, 64, 1.0 / COLS0);
  convLastStats_kernel<64><<<gb0, 256, 0, stream>>>(w02, c01, Z, st2);
  coef_kernel<<<1, 128, 0, stream>>>(st2, g02, b02, c02, 128, 1.0 / COLS0);
  convLastPool_kernel<64, 32><<<gb0, 256, 0, stream>>>(w02, c01, c02, Z, outFeats, 0);

  // ---- scale 1 (K=64): 67->64->96->128 ----
  convL0_kernel<64><<<gb1, 256, 0, stream>>>(w10, xyz, feat, nidx1, newxyz, Z, st3);
  coef_kernel<<<1, 128, 0, stream>>>(st3, g10, b10, c10, 64, 1.0 / COLS1);
  convMid_kernel<64, 96><<<gb1, 256, 0, stream>>>(w11, c10, Z, st4);
  coef_kernel<<<1, 128, 0, stream>>>(st4, g11, b11, c11, 96, 1.0 / COLS1);
  convLastStats_kernel<96><<<gb1, 256, 0, stream>>>(w12, c11, Z, st5);
  coef_kernel<<<1, 128, 0, stream>>>(st5, g12, b12, c12, 128, 1.0 / COLS1);
  convLastPool_kernel<96, 64><<<gb1, 256, 0, stream>>>(w12, c11, c12, Z, outFeats, 128);
}